// Round 1
// baseline (687.280 us; speedup 1.0000x reference)
//
#include <hip/hip_runtime.h>
#include <hip/hip_bf16.h>
#include <stdint.h>

#define B_ 8
#define T_ 2048
#define E_ 1024
#define H_ 1024
#define M_ (B_*T_)   // 16384

typedef __attribute__((ext_vector_type(8))) short bf16x8;
typedef __attribute__((ext_vector_type(4))) float f32x4;

__device__ __forceinline__ unsigned short f2bf(float f) {
  union { float f; unsigned int u; } v; v.f = f;
  unsigned int u = v.u;
  unsigned int r = u + 0x7fffu + ((u >> 16) & 1u);   // RNE (inputs finite)
  return (unsigned short)(r >> 16);
}

// ---------- convert x (fp32) -> xb (bf16), 8 elems / thread ----------
__global__ void conv_x_kernel(const float* __restrict__ x,
                              unsigned short* __restrict__ xb, int n8) {
  int i = blockIdx.x * blockDim.x + threadIdx.x;
  if (i >= n8) return;
  const float4* src = (const float4*)(x + (size_t)i * 8);
  float4 a = src[0], b = src[1];
  uint4 o;
  o.x = (unsigned)f2bf(a.x) | ((unsigned)f2bf(a.y) << 16);
  o.y = (unsigned)f2bf(a.z) | ((unsigned)f2bf(a.w) << 16);
  o.z = (unsigned)f2bf(b.x) | ((unsigned)f2bf(b.y) << 16);
  o.w = (unsigned)f2bf(b.z) | ((unsigned)f2bf(b.w) << 16);
  *(uint4*)(xb + (size_t)i * 8) = o;
}

// ---------- convert + transpose W (E x H fp32) -> wT (H x E bf16) ----------
__global__ void conv_wT_kernel(const float* __restrict__ W0, const float* __restrict__ W1,
                               const float* __restrict__ W2,
                               unsigned short* __restrict__ T0, unsigned short* __restrict__ T1,
                               unsigned short* __restrict__ T2) {
  __shared__ float tile[32][33];
  const float* W = (blockIdx.z == 0) ? W0 : (blockIdx.z == 1) ? W1 : W2;
  unsigned short* Tt = (blockIdx.z == 0) ? T0 : (blockIdx.z == 1) ? T1 : T2;
  int k0 = blockIdx.x * 32;
  int n0 = blockIdx.y * 32;
  int t = threadIdx.x;
#pragma unroll
  for (int i = 0; i < 4; ++i) {
    int e = t + i * 256; int r = e >> 5, c = e & 31;
    tile[r][c] = W[(size_t)(k0 + r) * H_ + n0 + c];
  }
  __syncthreads();
#pragma unroll
  for (int i = 0; i < 4; ++i) {
    int e = t + i * 256; int r = e >> 5, c = e & 31;   // r = n-local, c = k-local
    Tt[(size_t)(n0 + r) * E_ + k0 + c] = f2bf(tile[c][r]);
  }
}

// ---------- fused QKV GEMM: out = xb @ wT^T + bias ----------
// 128x128 tile, BK=64, 4 waves (2x2 of 64x64), mfma_f32_16x16x32_bf16
__global__ __launch_bounds__(256)
void gemm_qkv_kernel(const unsigned short* __restrict__ xb,
                     const unsigned short* __restrict__ wqT, const unsigned short* __restrict__ wkT,
                     const unsigned short* __restrict__ wvT,
                     const float* __restrict__ bq, const float* __restrict__ bk,
                     const float* __restrict__ bv,
                     unsigned short* __restrict__ qb, unsigned short* __restrict__ kb,
                     unsigned short* __restrict__ vb) {
  __shared__ short Alds[128 * 72];   // stride 72 elems = 144B (16B-aligned, 2-way-free banks)
  __shared__ short Blds[128 * 72];
  int which = blockIdx.y >> 3;
  int ncol0 = (blockIdx.y & 7) * 128;
  const unsigned short* Bt = (which == 0) ? wqT : (which == 1) ? wkT : wvT;
  const float* bias = (which == 0) ? bq : (which == 1) ? bk : bv;
  unsigned short* outp = (which == 0) ? qb : (which == 1) ? kb : vb;
  int m0 = blockIdx.x * 128;
  int tid = threadIdx.x, lane = tid & 63, wid = tid >> 6;
  int wm = (wid >> 1) * 64, wn = (wid & 1) * 64;

  f32x4 acc[4][4];
#pragma unroll
  for (int i = 0; i < 4; ++i)
#pragma unroll
    for (int j = 0; j < 4; ++j)
#pragma unroll
      for (int r = 0; r < 4; ++r) acc[i][j][r] = 0.f;

  for (int kb0 = 0; kb0 < E_; kb0 += 64) {
#pragma unroll
    for (int i = 0; i < 4; ++i) {
      int c = tid + i * 256;
      int row = c >> 3, k8 = (c & 7) * 8;
      *(uint4*)&Alds[row * 72 + k8] = *(const uint4*)(xb + (size_t)(m0 + row) * E_ + kb0 + k8);
      *(uint4*)&Blds[row * 72 + k8] = *(const uint4*)(Bt + (size_t)(ncol0 + row) * E_ + kb0 + k8);
    }
    __syncthreads();
#pragma unroll
    for (int kt = 0; kt < 2; ++kt) {
      bf16x8 af[4], bfr[4];
#pragma unroll
      for (int mt = 0; mt < 4; ++mt)
        af[mt] = *(const bf16x8*)&Alds[(wm + mt * 16 + (lane & 15)) * 72 + kt * 32 + (lane >> 4) * 8];
#pragma unroll
      for (int nt = 0; nt < 4; ++nt)
        bfr[nt] = *(const bf16x8*)&Blds[(wn + nt * 16 + (lane & 15)) * 72 + kt * 32 + (lane >> 4) * 8];
#pragma unroll
      for (int mt = 0; mt < 4; ++mt)
#pragma unroll
        for (int nt = 0; nt < 4; ++nt)
          acc[mt][nt] = __builtin_amdgcn_mfma_f32_16x16x32_bf16(af[mt], bfr[nt], acc[mt][nt], 0, 0, 0);
    }
    __syncthreads();
  }
#pragma unroll
  for (int nt = 0; nt < 4; ++nt) {
    int gcol = ncol0 + wn + nt * 16 + (lane & 15);
    float bb = bias[gcol];
#pragma unroll
    for (int mt = 0; mt < 4; ++mt) {
      int grow = m0 + wm + mt * 16 + (lane >> 4) * 4;
#pragma unroll
      for (int r = 0; r < 4; ++r)
        outp[(size_t)(grow + r) * H_ + gcol] = f2bf(acc[mt][nt][r] + bb);
    }
  }
}

// ---------- flash attention, causal, D=1024 ----------
// 8 waves/block, QB=32 q-rows, KB=32 keys/iter, wave w owns D-slice [w*128, w*128+128)
__global__ __launch_bounds__(512)
void attn_kernel(const unsigned short* __restrict__ qg, const unsigned short* __restrict__ kg,
                 const unsigned short* __restrict__ vg, float* __restrict__ out) {
  __shared__ float S_red[8][32][33];
  __shared__ float Ssum[32][32];
  __shared__ unsigned short P[32][40];   // stride 80B: aligned b128, 2-way-free
  __shared__ float m_s[32], l_s[32], a_s[32];

  int qt = blockIdx.x;          // q tile 0..63
  int b  = blockIdx.y;
  int tid = threadIdx.x, lane = tid & 63, wid = tid >> 6;
  int ds = wid * 128;
  size_t bT = (size_t)b * T_;
  int q0 = qt * 32;

  // Q fragments (resident): rows q0 + mt*16 + (lane&15), d = ds + kt*32 + (lane>>4)*8
  bf16x8 qf[2][4];
#pragma unroll
  for (int mt = 0; mt < 2; ++mt)
#pragma unroll
    for (int kt = 0; kt < 4; ++kt)
      qf[mt][kt] = *(const bf16x8*)(qg + (bT + q0 + mt * 16 + (lane & 15)) * H_ + ds + kt * 32 + (lane >> 4) * 8);

  f32x4 oacc[2][8];
#pragma unroll
  for (int mt = 0; mt < 2; ++mt)
#pragma unroll
    for (int nt = 0; nt < 8; ++nt)
#pragma unroll
      for (int r = 0; r < 4; ++r) oacc[mt][nt][r] = 0.f;

  if (tid < 32) { m_s[tid] = -1e30f; l_s[tid] = 0.f; }
  __syncthreads();

  for (int kbi = 0; kbi <= qt; ++kbi) {
    int k0 = kbi * 32;
    // ---- QK^T partial over this wave's D slice ----
    f32x4 sacc[2][2];
#pragma unroll
    for (int i = 0; i < 2; ++i)
#pragma unroll
      for (int j = 0; j < 2; ++j)
#pragma unroll
        for (int r = 0; r < 4; ++r) sacc[i][j][r] = 0.f;

    bf16x8 kf[2][4];
#pragma unroll
    for (int nt = 0; nt < 2; ++nt)
#pragma unroll
      for (int kt = 0; kt < 4; ++kt)
        kf[nt][kt] = *(const bf16x8*)(kg + (bT + k0 + nt * 16 + (lane & 15)) * H_ + ds + kt * 32 + (lane >> 4) * 8);
#pragma unroll
    for (int kt = 0; kt < 4; ++kt)
#pragma unroll
      for (int mt = 0; mt < 2; ++mt)
#pragma unroll
        for (int nt = 0; nt < 2; ++nt)
          sacc[mt][nt] = __builtin_amdgcn_mfma_f32_16x16x32_bf16(qf[mt][kt], kf[nt][kt], sacc[mt][nt], 0, 0, 0);

    // ---- prefetch V fragments (independent of softmax) ----
    bf16x8 vfr[8];
#pragma unroll
    for (int nt = 0; nt < 8; ++nt) {
      const unsigned short* vbase = vg + (bT + k0 + (lane >> 4) * 8) * H_ + ds + nt * 16 + (lane & 15);
      bf16x8 v;
#pragma unroll
      for (int j = 0; j < 8; ++j) v[j] = (short)vbase[(size_t)j * H_];
      vfr[nt] = v;
    }

    // ---- publish partial S ----
#pragma unroll
    for (int mt = 0; mt < 2; ++mt)
#pragma unroll
      for (int nt = 0; nt < 2; ++nt)
#pragma unroll
        for (int r = 0; r < 4; ++r)
          S_red[wid][mt * 16 + (lane >> 4) * 4 + r][nt * 16 + (lane & 15)] = sacc[mt][nt][r];
    __syncthreads();                                  // (1) S_red ready

    // ---- cross-wave reduce ----
#pragma unroll
    for (int i = 0; i < 2; ++i) {
      int e = tid + i * 512;
      int rr = e >> 5, cc = e & 31;
      float s = 0.f;
#pragma unroll
      for (int w = 0; w < 8; ++w) s += S_red[w][rr][cc];
      Ssum[rr][cc] = s;
    }
    __syncthreads();                                  // (2) Ssum ready

    // ---- wave-parallel online softmax: 2 rows/wave/pass, 2 passes ----
#pragma unroll
    for (int rr = 0; rr < 2; ++rr) {
      int row = rr * 16 + wid * 2 + (lane >> 5);
      int col = lane & 31;
      float s = Ssum[row][col] * 0.03125f;            // 1/sqrt(1024)
      if (k0 + col > q0 + row) s = -1e30f;            // causal mask
      float mx = s;
#pragma unroll
      for (int msk = 1; msk <= 16; msk <<= 1) mx = fmaxf(mx, __shfl_xor(mx, msk));
      float mo = m_s[row];
      float mn = fmaxf(mo, mx);
      float p = __expf(s - mn);
      float ps = p;
#pragma unroll
      for (int msk = 1; msk <= 16; msk <<= 1) ps += __shfl_xor(ps, msk);
      float al = __expf(mo - mn);
      if (col == 0) { m_s[row] = mn; l_s[row] = l_s[row] * al + ps; a_s[row] = al; }
      P[row][col] = f2bf(p);
    }
    __syncthreads();                                  // (3) P, a_s ready

    // ---- rescale O, then PV ----
#pragma unroll
    for (int mt = 0; mt < 2; ++mt) {
      float al[4];
#pragma unroll
      for (int r = 0; r < 4; ++r) al[r] = a_s[mt * 16 + (lane >> 4) * 4 + r];
#pragma unroll
      for (int nt = 0; nt < 8; ++nt)
#pragma unroll
        for (int r = 0; r < 4; ++r) oacc[mt][nt][r] *= al[r];
    }
    bf16x8 pa[2];
#pragma unroll
    for (int mt = 0; mt < 2; ++mt)
      pa[mt] = *(const bf16x8*)&P[mt * 16 + (lane & 15)][(lane >> 4) * 8];
#pragma unroll
    for (int nt = 0; nt < 8; ++nt)
#pragma unroll
      for (int mt = 0; mt < 2; ++mt)
        oacc[mt][nt] = __builtin_amdgcn_mfma_f32_16x16x32_bf16(pa[mt], vfr[nt], oacc[mt][nt], 0, 0, 0);
  }

  // ---- epilogue: O / l ----
#pragma unroll
  for (int mt = 0; mt < 2; ++mt) {
    float li[4];
#pragma unroll
    for (int r = 0; r < 4; ++r) li[r] = 1.0f / l_s[mt * 16 + (lane >> 4) * 4 + r];
#pragma unroll
    for (int nt = 0; nt < 8; ++nt)
#pragma unroll
      for (int r = 0; r < 4; ++r)
        out[(bT + q0 + mt * 16 + (lane >> 4) * 4 + r) * H_ + ds + nt * 16 + (lane & 15)] =
            oacc[mt][nt][r] * li[r];
  }
}

extern "C" void kernel_launch(void* const* d_in, const int* in_sizes, int n_in,
                              void* d_out, int out_size, void* d_ws, size_t ws_size,
                              hipStream_t stream) {
  const float* x  = (const float*)d_in[0];
  const float* Wq = (const float*)d_in[1];
  const float* bq = (const float*)d_in[2];
  const float* Wk = (const float*)d_in[3];
  const float* bk = (const float*)d_in[4];
  const float* Wv = (const float*)d_in[5];
  const float* bv = (const float*)d_in[6];
  float* out = (float*)d_out;

  unsigned short* ws = (unsigned short*)d_ws;
  unsigned short* xb  = ws;                              // M x E bf16
  unsigned short* wqT = xb  + (size_t)M_ * E_;           // H x E bf16 (transposed)
  unsigned short* wkT = wqT + (size_t)E_ * H_;
  unsigned short* wvT = wkT + (size_t)E_ * H_;
  unsigned short* qb  = wvT + (size_t)E_ * H_;           // M x H bf16
  unsigned short* kbp = qb  + (size_t)M_ * H_;
  unsigned short* vbp = kbp + (size_t)M_ * H_;

  conv_x_kernel<<<(M_ * E_ / 8 + 255) / 256, 256, 0, stream>>>(x, xb, M_ * E_ / 8);
  conv_wT_kernel<<<dim3(32, 32, 3), 256, 0, stream>>>(Wq, Wk, Wv, wqT, wkT, wvT);
  gemm_qkv_kernel<<<dim3(128, 24), 256, 0, stream>>>(xb, wqT, wkT, wvT, bq, bk, bv, qb, kbp, vbp);
  attn_kernel<<<dim3(64, 8), 512, 0, stream>>>(qb, kbp, vbp, out);
}

// Round 2
// 575.476 us; speedup vs baseline: 1.1943x; 1.1943x over previous
//
#include <hip/hip_runtime.h>
#include <hip/hip_bf16.h>
#include <stdint.h>

#define B_ 8
#define T_ 2048
#define E_ 1024
#define H_ 1024
#define M_ (B_*T_)   // 16384

typedef __attribute__((ext_vector_type(8))) short bf16x8;
typedef __attribute__((ext_vector_type(4))) float f32x4;

__device__ __forceinline__ unsigned short f2bf(float f) {
  union { float f; unsigned int u; } v; v.f = f;
  unsigned int u = v.u;
  unsigned int r = u + 0x7fffu + ((u >> 16) & 1u);   // RNE (inputs finite)
  return (unsigned short)(r >> 16);
}

// ---------- convert x (fp32) -> xb (bf16), 8 elems / thread ----------
__global__ void conv_x_kernel(const float* __restrict__ x,
                              unsigned short* __restrict__ xb, int n8) {
  int i = blockIdx.x * blockDim.x + threadIdx.x;
  if (i >= n8) return;
  const float4* src = (const float4*)(x + (size_t)i * 8);
  float4 a = src[0], b = src[1];
  uint4 o;
  o.x = (unsigned)f2bf(a.x) | ((unsigned)f2bf(a.y) << 16);
  o.y = (unsigned)f2bf(a.z) | ((unsigned)f2bf(a.w) << 16);
  o.z = (unsigned)f2bf(b.x) | ((unsigned)f2bf(b.y) << 16);
  o.w = (unsigned)f2bf(b.z) | ((unsigned)f2bf(b.w) << 16);
  *(uint4*)(xb + (size_t)i * 8) = o;
}

// ---------- convert + transpose W (E x H fp32) -> wT (H x E bf16) ----------
__global__ void conv_wT_kernel(const float* __restrict__ W0, const float* __restrict__ W1,
                               const float* __restrict__ W2,
                               unsigned short* __restrict__ T0, unsigned short* __restrict__ T1,
                               unsigned short* __restrict__ T2) {
  __shared__ float tile[32][33];
  const float* W = (blockIdx.z == 0) ? W0 : (blockIdx.z == 1) ? W1 : W2;
  unsigned short* Tt = (blockIdx.z == 0) ? T0 : (blockIdx.z == 1) ? T1 : T2;
  int k0 = blockIdx.x * 32;
  int n0 = blockIdx.y * 32;
  int t = threadIdx.x;
#pragma unroll
  for (int i = 0; i < 4; ++i) {
    int e = t + i * 256; int r = e >> 5, c = e & 31;
    tile[r][c] = W[(size_t)(k0 + r) * H_ + n0 + c];
  }
  __syncthreads();
#pragma unroll
  for (int i = 0; i < 4; ++i) {
    int e = t + i * 256; int r = e >> 5, c = e & 31;   // r = n-local, c = k-local
    Tt[(size_t)(n0 + r) * E_ + k0 + c] = f2bf(tile[c][r]);
  }
}

// ---------- fused QKV GEMM: out = xb @ wT^T + bias ----------
// 128x128 tile, BK=64, 4 waves (2x2 of 64x64), mfma_f32_16x16x32_bf16
// V (which==2) is written TRANSPOSED: vT[d][m], packed 8B stores.
__global__ __launch_bounds__(256)
void gemm_qkv_kernel(const unsigned short* __restrict__ xb,
                     const unsigned short* __restrict__ wqT, const unsigned short* __restrict__ wkT,
                     const unsigned short* __restrict__ wvT,
                     const float* __restrict__ bq, const float* __restrict__ bk,
                     const float* __restrict__ bv,
                     unsigned short* __restrict__ qb, unsigned short* __restrict__ kb,
                     unsigned short* __restrict__ vb) {
  __shared__ short Alds[128 * 72];   // stride 72 elems = 144B (16B-aligned, 2-way-free banks)
  __shared__ short Blds[128 * 72];
  int which = blockIdx.y >> 3;
  int ncol0 = (blockIdx.y & 7) * 128;
  const unsigned short* Bt = (which == 0) ? wqT : (which == 1) ? wkT : wvT;
  const float* bias = (which == 0) ? bq : (which == 1) ? bk : bv;
  unsigned short* outp = (which == 0) ? qb : (which == 1) ? kb : vb;
  int m0 = blockIdx.x * 128;
  int tid = threadIdx.x, lane = tid & 63, wid = tid >> 6;
  int wm = (wid >> 1) * 64, wn = (wid & 1) * 64;

  f32x4 acc[4][4];
#pragma unroll
  for (int i = 0; i < 4; ++i)
#pragma unroll
    for (int j = 0; j < 4; ++j)
#pragma unroll
      for (int r = 0; r < 4; ++r) acc[i][j][r] = 0.f;

  for (int kb0 = 0; kb0 < E_; kb0 += 64) {
#pragma unroll
    for (int i = 0; i < 4; ++i) {
      int c = tid + i * 256;
      int row = c >> 3, k8 = (c & 7) * 8;
      *(uint4*)&Alds[row * 72 + k8] = *(const uint4*)(xb + (size_t)(m0 + row) * E_ + kb0 + k8);
      *(uint4*)&Blds[row * 72 + k8] = *(const uint4*)(Bt + (size_t)(ncol0 + row) * E_ + kb0 + k8);
    }
    __syncthreads();
#pragma unroll
    for (int kt = 0; kt < 2; ++kt) {
      bf16x8 af[4], bfr[4];
#pragma unroll
      for (int mt = 0; mt < 4; ++mt)
        af[mt] = *(const bf16x8*)&Alds[(wm + mt * 16 + (lane & 15)) * 72 + kt * 32 + (lane >> 4) * 8];
#pragma unroll
      for (int nt = 0; nt < 4; ++nt)
        bfr[nt] = *(const bf16x8*)&Blds[(wn + nt * 16 + (lane & 15)) * 72 + kt * 32 + (lane >> 4) * 8];
#pragma unroll
      for (int mt = 0; mt < 4; ++mt)
#pragma unroll
        for (int nt = 0; nt < 4; ++nt)
          acc[mt][nt] = __builtin_amdgcn_mfma_f32_16x16x32_bf16(af[mt], bfr[nt], acc[mt][nt], 0, 0, 0);
    }
    __syncthreads();
  }
  if (which == 2) {
    // transposed write: vT[d = gcol][m = grow..grow+3], 8B packed
#pragma unroll
    for (int nt = 0; nt < 4; ++nt) {
      int gcol = ncol0 + wn + nt * 16 + (lane & 15);
      float bb = bias[gcol];
#pragma unroll
      for (int mt = 0; mt < 4; ++mt) {
        int grow = m0 + wm + mt * 16 + (lane >> 4) * 4;
        ushort4 o;
        o.x = f2bf(acc[mt][nt][0] + bb);
        o.y = f2bf(acc[mt][nt][1] + bb);
        o.z = f2bf(acc[mt][nt][2] + bb);
        o.w = f2bf(acc[mt][nt][3] + bb);
        *(ushort4*)(outp + (size_t)gcol * M_ + grow) = o;
      }
    }
  } else {
#pragma unroll
    for (int nt = 0; nt < 4; ++nt) {
      int gcol = ncol0 + wn + nt * 16 + (lane & 15);
      float bb = bias[gcol];
#pragma unroll
      for (int mt = 0; mt < 4; ++mt) {
        int grow = m0 + wm + mt * 16 + (lane >> 4) * 4;
#pragma unroll
        for (int r = 0; r < 4; ++r)
          outp[(size_t)(grow + r) * H_ + gcol] = f2bf(acc[mt][nt][r] + bb);
      }
    }
  }
}

// ---------- flash attention, causal, D=1024 ----------
// 8 waves/block. Per 256-key chunk: wave w computes full-D S chunk [32q x 32keys]
// (keys k0+w*32..), so no cross-wave S reduction. PV: wave w owns D-slice w*128.
// Q tile (32x1024 bf16) in swizzled LDS; P (32x256 bf16) in swizzled LDS.
// Block handles q-tile pair (j, 63-j): exactly 9 chunk-iterations.
__global__ __launch_bounds__(512)
void attn_kernel(const unsigned short* __restrict__ qg, const unsigned short* __restrict__ kg,
                 const unsigned short* __restrict__ vT, float* __restrict__ out) {
  __shared__ char Qlds[32 * 2048];      // 64KB, row stride 2048B, swz ^((row&7)<<4)
  __shared__ char Plds[32 * 512];       // 16KB, row stride 512B,  swz ^((row&7)<<4)
  __shared__ float wred[32 * 16];       // [row][0..7]=max part, [8..15]=sum part, swz ^(((row>>2)&3)<<4)

  const int bid = blockIdx.x;
  const int b = bid & 7, pj = bid >> 3;       // batch fastest -> same batch per XCD (heuristic)
  const size_t bT = (size_t)b * T_;
  const int tid = threadIdx.x, lane = tid & 63, w = tid >> 6;
  const int hi = lane >> 4, lo = lane & 15;
  const int ds = w * 128;

  for (int phase = 0; phase < 2; ++phase) {
    const int qt = (phase == 0) ? pj : 63 - pj;
    const int q0 = qt * 32;

    // ---- stage Q tile (32 x 1024), swizzled ----
    for (int e = tid; e < 4096; e += 512) {
      int row = e >> 7, c16 = e & 127;
      uint4 v = *(const uint4*)(qg + (bT + q0 + row) * (size_t)H_ + c16 * 8);
      int byte = (row << 11) | (c16 << 4);
      *(uint4*)(Qlds + (byte ^ ((row & 7) << 4))) = v;
    }

    float m_run[2][4], l_run[2][4];
    f32x4 oacc[2][8];
#pragma unroll
    for (int mt = 0; mt < 2; ++mt) {
#pragma unroll
      for (int r = 0; r < 4; ++r) { m_run[mt][r] = -1e30f; l_run[mt][r] = 0.f; }
#pragma unroll
      for (int nt = 0; nt < 8; ++nt)
#pragma unroll
        for (int r = 0; r < 4; ++r) oacc[mt][nt][r] = 0.f;
    }
    __syncthreads();   // Q staged

    const int nkb = (qt >> 3) + 1;
    for (int kbi = 0; kbi < nkb; ++kbi) {
      const int k0 = kbi << 8;
      const int kw = k0 + w * 32;              // this wave's key base
      const bool active = kw <= q0 + 31;       // wave-uniform

      // ---- QK^T: full-D S chunk [32 x 32] for this wave's keys ----
      f32x4 sacc[2][2];
#pragma unroll
      for (int i = 0; i < 2; ++i)
#pragma unroll
        for (int j = 0; j < 2; ++j)
#pragma unroll
          for (int r = 0; r < 4; ++r) sacc[i][j][r] = 0.f;

      if (active) {
        const unsigned short* kp = kg + (bT + kw + lo) * (size_t)H_ + hi * 8;
        bf16x8 kf0 = *(const bf16x8*)kp;
        bf16x8 kf1 = *(const bf16x8*)(kp + 16 * H_);
        const int qb0 = (lo << 11) | (hi << 4);
        const int qb1 = ((16 + lo) << 11) | (hi << 4);
        const int qswz = (lo & 7) << 4;
#pragma unroll 4
        for (int kt = 0; kt < 32; ++kt) {
          bf16x8 kn0, kn1;
          if (kt < 31) {
            kn0 = *(const bf16x8*)(kp + (kt + 1) * 32);
            kn1 = *(const bf16x8*)(kp + 16 * H_ + (kt + 1) * 32);
          }
          bf16x8 a0 = *(const bf16x8*)(Qlds + ((qb0 + (kt << 6)) ^ qswz));
          bf16x8 a1 = *(const bf16x8*)(Qlds + ((qb1 + (kt << 6)) ^ qswz));
          sacc[0][0] = __builtin_amdgcn_mfma_f32_16x16x32_bf16(a0, kf0, sacc[0][0], 0, 0, 0);
          sacc[0][1] = __builtin_amdgcn_mfma_f32_16x16x32_bf16(a0, kf1, sacc[0][1], 0, 0, 0);
          sacc[1][0] = __builtin_amdgcn_mfma_f32_16x16x32_bf16(a1, kf0, sacc[1][0], 0, 0, 0);
          sacc[1][1] = __builtin_amdgcn_mfma_f32_16x16x32_bf16(a1, kf1, sacc[1][1], 0, 0, 0);
          if (kt < 31) { kf0 = kn0; kf1 = kn1; }
        }
      }

      // ---- masked scale + wave-partial rowmax ----
      float sm[2][2][4];
      float pm[2][4];
#pragma unroll
      for (int mt = 0; mt < 2; ++mt)
#pragma unroll
        for (int r = 0; r < 4; ++r) {
          const int gq = q0 + mt * 16 + hi * 4 + r;
          float v0 = (active && (kw + lo) <= gq)      ? sacc[mt][0][r] * 0.03125f : -1e30f;
          float v1 = (active && (kw + 16 + lo) <= gq) ? sacc[mt][1][r] * 0.03125f : -1e30f;
          sm[mt][0][r] = v0; sm[mt][1][r] = v1;
          pm[mt][r] = fmaxf(v0, v1);
        }
#pragma unroll
      for (int msk = 1; msk <= 8; msk <<= 1)
#pragma unroll
        for (int mt = 0; mt < 2; ++mt)
#pragma unroll
          for (int r = 0; r < 4; ++r)
            pm[mt][r] = fmaxf(pm[mt][r], __shfl_xor(pm[mt][r], msk));
      if (lo == 0) {
#pragma unroll
        for (int mt = 0; mt < 2; ++mt)
#pragma unroll
          for (int r = 0; r < 4; ++r) {
            int row = mt * 16 + hi * 4 + r;
            int byte = (row << 6) | (w << 2);
            *(float*)((char*)wred + (byte ^ (((row >> 2) & 3) << 4))) = pm[mt][r];
          }
      }
      __syncthreads();   // B1: wmax partials ready

      // ---- global row max, p = exp(s - m), write P, partial row sums ----
      float mn[2][4], ps[2][4];
#pragma unroll
      for (int mt = 0; mt < 2; ++mt)
#pragma unroll
        for (int r = 0; r < 4; ++r) {
          const int row = mt * 16 + hi * 4 + r;
          const int base = row << 6;
          const int wsz = ((row >> 2) & 3) << 4;
          float4 w0 = *(const float4*)((char*)wred + ((base + 0) ^ wsz));
          float4 w1 = *(const float4*)((char*)wred + ((base + 16) ^ wsz));
          float mx = fmaxf(fmaxf(fmaxf(w0.x, w0.y), fmaxf(w0.z, w0.w)),
                           fmaxf(fmaxf(w1.x, w1.y), fmaxf(w1.z, w1.w)));
          float m2 = fmaxf(m_run[mt][r], mx);
          mn[mt][r] = m2;
          float p0 = __expf(sm[mt][0][r] - m2);
          float p1 = __expf(sm[mt][1][r] - m2);
          const int pswz = (row & 7) << 4;
          const int pb = (row << 9) | (w << 6) | (lo << 1);
          *(unsigned short*)(Plds + (pb ^ pswz)) = f2bf(p0);
          *(unsigned short*)(Plds + ((pb | 32) ^ pswz)) = f2bf(p1);
          ps[mt][r] = p0 + p1;
        }
#pragma unroll
      for (int msk = 1; msk <= 8; msk <<= 1)
#pragma unroll
        for (int mt = 0; mt < 2; ++mt)
#pragma unroll
          for (int r = 0; r < 4; ++r)
            ps[mt][r] += __shfl_xor(ps[mt][r], msk);
      if (lo == 0) {
#pragma unroll
        for (int mt = 0; mt < 2; ++mt)
#pragma unroll
          for (int r = 0; r < 4; ++r) {
            int row = mt * 16 + hi * 4 + r;
            int byte = (row << 6) | ((8 + w) << 2);
            *(float*)((char*)wred + (byte ^ (((row >> 2) & 3) << 4))) = ps[mt][r];
          }
      }
      __syncthreads();   // B2: P + sum partials ready

      // ---- l/m update + O rescale ----
#pragma unroll
      for (int mt = 0; mt < 2; ++mt)
#pragma unroll
        for (int r = 0; r < 4; ++r) {
          const int row = mt * 16 + hi * 4 + r;
          const int base = row << 6;
          const int wsz = ((row >> 2) & 3) << 4;
          float4 s0 = *(const float4*)((char*)wred + ((base + 32) ^ wsz));
          float4 s1 = *(const float4*)((char*)wred + ((base + 48) ^ wsz));
          float lsum = (s0.x + s0.y) + (s0.z + s0.w) + (s1.x + s1.y) + (s1.z + s1.w);
          float a = __expf(m_run[mt][r] - mn[mt][r]);
          m_run[mt][r] = mn[mt][r];
          l_run[mt][r] = l_run[mt][r] * a + lsum;
#pragma unroll
          for (int nt = 0; nt < 8; ++nt) oacc[mt][nt][r] *= a;
        }

      // ---- PV: wave's D-slice [ds, ds+128), K-dim = 256 keys ----
      const unsigned short* vp = vT + bT + k0 + hi * 8;
      bf16x8 vf[8];
#pragma unroll
      for (int nt = 0; nt < 8; ++nt)
        vf[nt] = *(const bf16x8*)(vp + (size_t)(ds + nt * 16 + lo) * M_);
      const int pb0 = (lo << 9) | (hi << 4);
      const int pb1 = ((16 + lo) << 9) | (hi << 4);
      const int pswz = (lo & 7) << 4;
#pragma unroll
      for (int kt = 0; kt < 8; ++kt) {
        bf16x8 vn[8];
        if (kt < 7) {
#pragma unroll
          for (int nt = 0; nt < 8; ++nt)
            vn[nt] = *(const bf16x8*)(vp + (size_t)(ds + nt * 16 + lo) * M_ + (kt + 1) * 32);
        }
        bf16x8 p0 = *(const bf16x8*)(Plds + ((pb0 + (kt << 6)) ^ pswz));
        bf16x8 p1 = *(const bf16x8*)(Plds + ((pb1 + (kt << 6)) ^ pswz));
#pragma unroll
        for (int nt = 0; nt < 8; ++nt) {
          oacc[0][nt] = __builtin_amdgcn_mfma_f32_16x16x32_bf16(p0, vf[nt], oacc[0][nt], 0, 0, 0);
          oacc[1][nt] = __builtin_amdgcn_mfma_f32_16x16x32_bf16(p1, vf[nt], oacc[1][nt], 0, 0, 0);
        }
        if (kt < 7) {
#pragma unroll
          for (int nt = 0; nt < 8; ++nt) vf[nt] = vn[nt];
        }
      }
      __syncthreads();   // B3: PV done -> next iter may overwrite P/wred
    }

    // ---- epilogue: O / l ----
#pragma unroll
    for (int mt = 0; mt < 2; ++mt)
#pragma unroll
      for (int r = 0; r < 4; ++r) {
        float li = 1.0f / l_run[mt][r];
        const size_t rb = (bT + q0 + mt * 16 + hi * 4 + r) * (size_t)H_ + ds + lo;
#pragma unroll
        for (int nt = 0; nt < 8; ++nt)
          out[rb + nt * 16] = oacc[mt][nt][r] * li;
      }
  }
}

extern "C" void kernel_launch(void* const* d_in, const int* in_sizes, int n_in,
                              void* d_out, int out_size, void* d_ws, size_t ws_size,
                              hipStream_t stream) {
  const float* x  = (const float*)d_in[0];
  const float* Wq = (const float*)d_in[1];
  const float* bq = (const float*)d_in[2];
  const float* Wk = (const float*)d_in[3];
  const float* bk = (const float*)d_in[4];
  const float* Wv = (const float*)d_in[5];
  const float* bv = (const float*)d_in[6];
  float* out = (float*)d_out;

  unsigned short* ws = (unsigned short*)d_ws;
  unsigned short* xb  = ws;                              // M x E bf16
  unsigned short* wqT = xb  + (size_t)M_ * E_;           // H x E bf16 (transposed)
  unsigned short* wkT = wqT + (size_t)E_ * H_;
  unsigned short* wvT = wkT + (size_t)E_ * H_;
  unsigned short* qb  = wvT + (size_t)E_ * H_;           // M x H bf16
  unsigned short* kbp = qb  + (size_t)M_ * H_;
  unsigned short* vTp = kbp + (size_t)M_ * H_;           // H x M bf16 (V transposed)

  conv_x_kernel<<<(M_ * E_ / 8 + 255) / 256, 256, 0, stream>>>(x, xb, M_ * E_ / 8);
  conv_wT_kernel<<<dim3(32, 32, 3), 256, 0, stream>>>(Wq, Wk, Wv, wqT, wkT, wvT);
  gemm_qkv_kernel<<<dim3(128, 24), 256, 0, stream>>>(xb, wqT, wkT, wvT, bq, bk, bv, qb, kbp, vTp);
  attn_kernel<<<dim3(256), 512, 0, stream>>>(qb, kbp, vTp, out);
}